// Round 10
// baseline (369.581 us; speedup 1.0000x reference)
//
#include <hip/hip_runtime.h>
#include <hip/hip_bf16.h>
#include <cstdio>

#define F 128
#define BSHIFT 9
#define BROWS 512   // rows per bucket (N must be <= 131072 for the 17-bit src pack)
#define C2 4096     // edges per bucket_scatter block

typedef __attribute__((ext_vector_type(4))) float f32x4;
typedef __attribute__((ext_vector_type(4))) unsigned short u16x4;
typedef __attribute__((ext_vector_type(8))) short s16x8;

__device__ inline unsigned short f2bf(float x) {
  unsigned int u = __float_as_uint(x);
  u += 0x7fffu + ((u >> 16) & 1u);   // RNE
  return (unsigned short)(u >> 16);
}
__device__ inline float bf2f(unsigned int h) {
  return __uint_as_float(h << 16);
}

__device__ inline void async_load16(const void* g, void* l) {
  __builtin_amdgcn_global_load_lds(
      (const __attribute__((address_space(1))) void*)g,
      (__attribute__((address_space(3))) void*)l, 16, 0, 0);
}

// ---------------- bucket histogram (LDS-aggregated) ----------------
__global__ void bucket_hist_kernel(const int* __restrict__ dst, int* __restrict__ bhist,
                                   int E, int B) {
  __shared__ int h[256];
  int t = threadIdx.x;
  h[t] = 0;
  __syncthreads();
  for (int e = blockIdx.x * blockDim.x + t; e < E; e += gridDim.x * blockDim.x)
    atomicAdd(&h[dst[e] >> BSHIFT], 1);
  __syncthreads();
  if (t < B && h[t]) atomicAdd(&bhist[t], h[t]);
}

// ---------------- bucket scan: bases (== rp at bucket boundaries) ----------------
__global__ void bucket_scan_kernel(const int* __restrict__ bhist, int* __restrict__ bbase,
                                   int* __restrict__ bcursor, int* __restrict__ rp,
                                   int E, int B, int N) {
  __shared__ int sm[256];
  int t = threadIdx.x;
  int v = (t < B) ? bhist[t] : 0;
  sm[t] = v;
  __syncthreads();
  int x = v;
  for (int off = 1; off < 256; off <<= 1) {
    int add = (t >= off) ? sm[t - off] : 0;
    __syncthreads();
    x += add;
    sm[t] = x;
    __syncthreads();
  }
  int excl = x - v;
  if (t < B) { bbase[t] = excl; bcursor[t] = excl; }
  if (t == 0) { bbase[B] = E; rp[N] = E; }
}

// ---------------- grouped bucket scatter: edges -> bucket-major staging ----------------
__global__ __launch_bounds__(256) void bucket_scatter_kernel(
    const int* __restrict__ src, const int* __restrict__ dst, const float* __restrict__ ew,
    int* __restrict__ bcursor, unsigned int* __restrict__ stg_p, float* __restrict__ stg_w,
    int E, int B) {
  __shared__ int hist[256], gbase[256], cur[256], sm[256], scn[256];
  __shared__ unsigned int sp[C2];
  __shared__ float swt[C2];
  __shared__ int sdest[C2];
  int t = threadIdx.x;
  int e0 = blockIdx.x * C2;
  int cnt = min(C2, E - e0);
  hist[t] = 0;
  __syncthreads();
#pragma unroll
  for (int i = 0; i < C2 / 256; ++i) {
    int e = e0 + t + i * 256;
    if (e < E) atomicAdd(&hist[dst[e] >> BSHIFT], 1);
  }
  __syncthreads();
  int v = hist[t];
  gbase[t] = (t < B && v) ? atomicAdd(&bcursor[t], v) : 0;
  sm[t] = v;
  __syncthreads();
  int x = v;
  for (int off = 1; off < 256; off <<= 1) {
    int add = (t >= off) ? sm[t - off] : 0;
    __syncthreads();
    x += add;
    sm[t] = x;
    __syncthreads();
  }
  scn[t] = x - v;
  cur[t] = 0;
  __syncthreads();
#pragma unroll
  for (int i = 0; i < C2 / 256; ++i) {
    int e = e0 + t + i * 256;
    if (e < E) {
      int d = dst[e];
      int b = d >> BSHIFT;
      int r = atomicAdd(&cur[b], 1);
      int slot = scn[b] + r;
      sp[slot] = (unsigned int)src[e] | ((unsigned int)(d & (BROWS - 1)) << 17);
      swt[slot] = ew[e];
      sdest[slot] = gbase[b] + r;
    }
  }
  __syncthreads();
#pragma unroll
  for (int i = 0; i < C2 / 256; ++i) {
    int s = t + i * 256;
    if (s < cnt) {
      int dpos = sdest[s];
      stg_p[dpos] = sp[s];
      stg_w[dpos] = swt[s];
    }
  }
}

// ---------------- per-bucket CSR finalize (also produces rp) ----------------
__global__ __launch_bounds__(256) void csr_build_kernel(
    const unsigned int* __restrict__ stg_p, const float* __restrict__ stg_w,
    const int* __restrict__ bbase, int* __restrict__ rp, int2* __restrict__ csr,
    int N, int B) {
  __shared__ int rhist[BROWS], rloc[BROWS], curp[BROWS];
  __shared__ int sm[256];
  int b = blockIdx.x, t = threadIdx.x;
  int row0 = b << BSHIFT;
  int base = bbase[b];
  int cnt = bbase[b + 1] - base;
  rhist[t] = 0;
  rhist[t + 256] = 0;
  __syncthreads();
  for (int s = base + t; s < base + cnt; s += 256)
    atomicAdd(&rhist[stg_p[s] >> 17], 1);
  __syncthreads();
  int a0 = rhist[2 * t], a1 = rhist[2 * t + 1];
  int pv = a0 + a1;
  sm[t] = pv;
  __syncthreads();
  int x = pv;
  for (int off = 1; off < 256; off <<= 1) {
    int add = (t >= off) ? sm[t - off] : 0;
    __syncthreads();
    x += add;
    sm[t] = x;
    __syncthreads();
  }
  int pexcl = x - pv;
  int r0 = 2 * t, r1 = 2 * t + 1;
  rloc[r0] = pexcl;
  rloc[r1] = pexcl + a0;
  if (row0 + r0 < N) rp[row0 + r0] = base + rloc[r0];
  if (row0 + r1 < N) rp[row0 + r1] = base + rloc[r1];
  curp[r0] = base + rloc[r0];
  curp[r1] = base + rloc[r1];
  __syncthreads();
  for (int s = base + t; s < base + cnt; s += 256) {
    unsigned int p = stg_p[s];
    int dl = p >> 17;
    int pos = atomicAdd(&curp[dl], 1);
    int2 entry;
    entry.x = (int)(p & 0x1ffffu);
    entry.y = __float_as_int(stg_w[s]);
    csr[pos] = entry;   // random 8B but confined to this bucket's ~64KB window
  }
}

// ---------------- x fp32 -> bf16 ----------------
__global__ void convx_kernel(const float* __restrict__ x, unsigned short* __restrict__ xbf,
                             int total4) {
  int i = blockIdx.x * 256 + threadIdx.x;
  if (i >= total4) return;
  f32x4 v = ((const f32x4*)x)[i];
  u16x4 o;
  o.x = f2bf(v.x); o.y = f2bf(v.y); o.z = f2bf(v.z); o.w = f2bf(v.w);
  ((u16x4*)xbf)[i] = o;
}

// ---------------- SPMM v4: 16-lane group per row, 8-deep gather pipeline ----------------
// Tout[r] = bf16( scale * sum_j w_j * Tin[src_j] - Tsub[r] )
__global__ __launch_bounds__(256) void spmm_kernel(
    const unsigned short* __restrict__ Tin, const unsigned short* __restrict__ Tsub,
    unsigned short* __restrict__ Tout, const int* __restrict__ rp,
    const int2* __restrict__ csr, int n, float scale) {
  int row = blockIdx.x * 16 + (threadIdx.x >> 4);
  if (row >= n) return;
  int sl = threadIdx.x & 15;   // 16B column slice within the row
  int j0 = rp[row], end = rp[row + 1];
  const uint4* Tin4 = (const uint4*)Tin;
  float acc[8];
#pragma unroll
  for (int c = 0; c < 8; ++c) acc[c] = 0.f;

  for (int j = j0; j < end; j += 8) {
    int2 e[8];
#pragma unroll
    for (int u = 0; u < 8; ++u)
      if (j + u < end) e[u] = csr[j + u];
    uint4 v[8];
#pragma unroll
    for (int u = 0; u < 8; ++u)
      if (j + u < end) v[u] = Tin4[(size_t)e[u].x * 16 + sl];
#pragma unroll
    for (int u = 0; u < 8; ++u) {
      if (j + u < end) {
        float w = __int_as_float(e[u].y);
        acc[0] = fmaf(w, bf2f(v[u].x & 0xffffu), acc[0]);
        acc[1] = fmaf(w, bf2f(v[u].x >> 16), acc[1]);
        acc[2] = fmaf(w, bf2f(v[u].y & 0xffffu), acc[2]);
        acc[3] = fmaf(w, bf2f(v[u].y >> 16), acc[3]);
        acc[4] = fmaf(w, bf2f(v[u].z & 0xffffu), acc[4]);
        acc[5] = fmaf(w, bf2f(v[u].z >> 16), acc[5]);
        acc[6] = fmaf(w, bf2f(v[u].w & 0xffffu), acc[6]);
        acc[7] = fmaf(w, bf2f(v[u].w >> 16), acc[7]);
      }
    }
  }

  float r[8];
#pragma unroll
  for (int c = 0; c < 8; ++c) r[c] = scale * acc[c];
  if (Tsub) {
    uint4 p = ((const uint4*)Tsub)[(size_t)row * 16 + sl];
    r[0] -= bf2f(p.x & 0xffffu); r[1] -= bf2f(p.x >> 16);
    r[2] -= bf2f(p.y & 0xffffu); r[3] -= bf2f(p.y >> 16);
    r[4] -= bf2f(p.z & 0xffffu); r[5] -= bf2f(p.z >> 16);
    r[6] -= bf2f(p.w & 0xffffu); r[7] -= bf2f(p.w >> 16);
  }
  uint4 o;
  o.x = (unsigned)f2bf(r[0]) | ((unsigned)f2bf(r[1]) << 16);
  o.y = (unsigned)f2bf(r[2]) | ((unsigned)f2bf(r[3]) << 16);
  o.z = (unsigned)f2bf(r[4]) | ((unsigned)f2bf(r[5]) << 16);
  o.w = (unsigned)f2bf(r[6]) | ((unsigned)f2bf(r[7]) << 16);
  ((uint4*)Tout)[(size_t)row * 16 + sl] = o;
}

// ---------------- W -> MFMA-fragment-major bf16 pack ----------------
// Wf[((ks*4+kk)*8+nt)*512 + lane*8 + j] = bf16(W[ks][kk*32+(lane>>4)*8+j][nt*16+(lane&15)])
__global__ void convw_kernel(const float* __restrict__ W, unsigned short* __restrict__ Wf,
                             int total) {
  int idx = blockIdx.x * 256 + threadIdx.x;
  if (idx >= total) return;
  int j = idx & 7;
  int lane = (idx >> 3) & 63;
  int nt = (idx >> 9) & 7;
  int kk = (idx >> 12) & 3;
  int ks = idx >> 14;
  int kl = kk * 32 + (lane >> 4) * 8 + j;
  int col = nt * 16 + (lane & 15);
  Wf[idx] = f2bf(W[(size_t)ks * F * F + (size_t)kl * F + col]);
}

// ---------------- GEMM v7: BOTH operands via global_load_lds DMA, frags via ds_read ----
// out[i,:] = sum_ks fc[ks,i] * (T_ks[i,:] @ W[ks]) + bias
// No direct-to-register global loads anywhere in the K-loop (they get latency-
// serialized by regalloc: v3/v4/v6 all 64-75us). Staging is DMA (zero VGPR);
// fragment reads are ds_read_b128 at frag_base + lane*16 (0-conflict pattern).
// A staged fragment-major via pre-swizzled per-lane global source addresses.
struct GemmArgs {
  const unsigned short* A[8];
  const float* fc;
  const unsigned short* Wt;
  const float* bias;
  float* out;
  int n;
  int kslices;
};

__global__ __launch_bounds__(512) void gemm_kernel(GemmArgs args) {
  __shared__ __align__(16) unsigned short SA[16384];   // 32KB: A tile, fragment-major
  __shared__ __align__(16) unsigned short SB[16384];   // 32KB: B (one ks of Wf)
  const int t = threadIdx.x;
  const int lane = t & 63;
  const int wid = t >> 6;          // 0..7
  const int wrow = wid >> 1;       // 0..3 (32-row slice)
  const int wcol = wid & 1;        // 0..1 (64-col slice)
  const int n = args.n;
  const int bm = blockIdx.x * 128;
  const int arow = lane & 15;
  const int kg = lane >> 4;

  f32x4 Cf[2][4];
#pragma unroll
  for (int mt = 0; mt < 2; ++mt)
#pragma unroll
    for (int nt = 0; nt < 4; ++nt) Cf[mt][nt] = (f32x4){0.f, 0.f, 0.f, 0.f};

  for (int ks = 0; ks < args.kslices; ++ks) {
    const unsigned short* As = args.A[ks];
    // ---- stage A fragment-major: frag fi = rg*4+kk (rg=16-row group, kk=32-k chunk)
    // lane l of frag fi sources A[bm+rg*16+(l&15)][kk*32+(l>>4)*8 .. +8].
    // Wave stages frags fi = wid + i*8 (LDS dest wave-uniform base + lane*16).
#pragma unroll
    for (int i = 0; i < 4; ++i) {
      int fi = wid + i * 8;
      int rg = fi >> 2, kk = fi & 3;
      int r = bm + rg * 16 + arow;
      if (r >= n) r = n - 1;
      const void* g = (const void*)(As + (size_t)r * F + kk * 32 + kg * 8);
      async_load16(g, (void*)(SA + fi * 512));
    }
    // ---- stage B linear (Wf already fragment-major): frag fi, 16B per lane
#pragma unroll
    for (int i = 0; i < 4; ++i) {
      int fi = wid + i * 8;
      const void* g = (const void*)(args.Wt + (size_t)ks * 16384 + fi * 512 + lane * 8);
      async_load16(g, (void*)(SB + fi * 512));
    }
    __syncthreads();   // drain DMA; tiles visible

    // ---- MFMA: frags from LDS (ds_read_b128, frag_base + lane*16)
    f32x4 acc[2][4];
#pragma unroll
    for (int mt = 0; mt < 2; ++mt)
#pragma unroll
      for (int nt = 0; nt < 4; ++nt) acc[mt][nt] = (f32x4){0.f, 0.f, 0.f, 0.f};

#pragma unroll
    for (int kk = 0; kk < 4; ++kk) {
      s16x8 af[2], bfr[4];
#pragma unroll
      for (int mt = 0; mt < 2; ++mt) {
        int rg = wrow * 2 + mt;
        af[mt] = *(const s16x8*)&SA[(rg * 4 + kk) * 512 + lane * 8];
      }
#pragma unroll
      for (int nt = 0; nt < 4; ++nt)
        bfr[nt] = *(const s16x8*)&SB[(kk * 8 + wcol * 4 + nt) * 512 + lane * 8];
#pragma unroll
      for (int mt = 0; mt < 2; ++mt)
#pragma unroll
        for (int nt = 0; nt < 4; ++nt)
          acc[mt][nt] = __builtin_amdgcn_mfma_f32_16x16x32_bf16(af[mt], bfr[nt],
                                                                acc[mt][nt], 0, 0, 0);
    }

    // ---- merge: Cf += fc[ks,row] * acc  (fp32; acc row = kg*4 + reg)
#pragma unroll
    for (int mt = 0; mt < 2; ++mt) {
      int row = bm + wrow * 32 + mt * 16 + kg * 4;
      f32x4 fv;
      if (row + 3 < n) {
        fv = *(const f32x4*)(args.fc + (size_t)ks * n + row);
      } else {
#pragma unroll
        for (int r4 = 0; r4 < 4; ++r4) {
          int rr = row + r4;
          if (rr >= n) rr = n - 1;
          fv[r4] = args.fc[(size_t)ks * n + rr];
        }
      }
#pragma unroll
      for (int nt = 0; nt < 4; ++nt) Cf[mt][nt] += fv * acc[mt][nt];
    }
    __syncthreads();   // all frag reads done before next ks restages
  }

  // epilogue: C/D layout col=lane&15, row=(lane>>4)*4+reg
#pragma unroll
  for (int nt = 0; nt < 4; ++nt) {
    int col = (wcol * 4 + nt) * 16 + arow;
    float bv = args.bias[col];
#pragma unroll
    for (int mt = 0; mt < 2; ++mt) {
#pragma unroll
      for (int r4 = 0; r4 < 4; ++r4) {
        int row = bm + wrow * 32 + mt * 16 + kg * 4 + r4;
        if (row < n) args.out[(size_t)row * F + col] = Cf[mt][nt][r4] + bv;
      }
    }
  }
}

extern "C" void kernel_launch(void* const* d_in, const int* in_sizes, int n_in,
                              void* d_out, int out_size, void* d_ws, size_t ws_size,
                              hipStream_t stream) {
  const float* x    = (const float*)d_in[0];
  const float* fc   = (const float*)d_in[1];
  const float* W    = (const float*)d_in[2];
  const float* bias = (const float*)d_in[3];
  const float* ew   = (const float*)d_in[4];
  const int*   src  = (const int*)d_in[5];
  const int*   dst  = (const int*)d_in[6];

  const int N = in_sizes[0] / F;
  const int K = in_sizes[2] / (F * F);
  const int E = in_sizes[4];
  const int B = (N + BROWS - 1) >> BSHIFT;   // buckets; requires N <= 131072

  size_t off = 0;
  char* base = (char*)d_ws;
  auto alloc = [&](size_t bytes) -> void* {
    void* p = base + off;
    off += (bytes + 511) & ~(size_t)511;
    return p;
  };
  int* rp              = (int*)alloc(((size_t)N + 1) * 4);
  int* bhist           = (int*)alloc(1024);
  int* bbase           = (int*)alloc(1040);
  int* bcursor         = (int*)alloc(1024);
  int2* csr            = (int2*)alloc((size_t)E * 8);
  unsigned short* Wt   = (unsigned short*)alloc((size_t)K * F * F * 2);
  unsigned short* xbf  = (unsigned short*)alloc((size_t)N * F * 2);
  unsigned short* T[8];
  T[0] = xbf;
  for (int k = 1; k < K && k < 8; ++k) T[k] = (unsigned short*)alloc((size_t)N * F * 2);
  // staging aliased onto T[2] (written only after CSR build); fallback alloc if K<3
  unsigned int* stg_p;
  float* stg_w;
  if (K >= 3 && (size_t)N * F * 2 >= (size_t)E * 8) {
    stg_p = (unsigned int*)T[2];
    stg_w = (float*)(T[2] + (size_t)E * 2);  // E*2 ushorts == E*4 bytes
  } else {
    stg_p = (unsigned int*)alloc((size_t)E * 4);
    stg_w = (float*)alloc((size_t)E * 4);
  }
  if (off > ws_size) {
    fprintf(stderr, "kernel_launch: ws too small: need %zu have %zu\n", off, ws_size);
    return;
  }

  // ---- CSR build (bucketed) ----
  hipMemsetAsync(bhist, 0, 1024, stream);
  int hblocks = (E + 255) / 256;
  if (hblocks > 2048) hblocks = 2048;
  hipLaunchKernelGGL(bucket_hist_kernel, dim3(hblocks), dim3(256), 0, stream, dst, bhist, E, B);
  hipLaunchKernelGGL(bucket_scan_kernel, dim3(1), dim3(256), 0, stream, bhist, bbase, bcursor,
                     rp, E, B, N);
  int sblocks = (E + C2 - 1) / C2;
  hipLaunchKernelGGL(bucket_scatter_kernel, dim3(sblocks), dim3(256), 0, stream, src, dst, ew,
                     bcursor, stg_p, stg_w, E, B);
  hipLaunchKernelGGL(csr_build_kernel, dim3(B), dim3(256), 0, stream, stg_p, stg_w, bbase,
                     rp, csr, N, B);

  // ---- x -> bf16 ----
  int total4 = N * F / 4;
  hipLaunchKernelGGL(convx_kernel, dim3((total4 + 255) / 256), dim3(256), 0, stream,
                     x, xbf, total4);

  // ---- Chebyshev recurrence (bf16 state, fp32 accum) ----
  int sb = (N + 15) / 16;  // 16 rows (16-lane groups) per 256-thread block
  if (K > 1)
    hipLaunchKernelGGL(spmm_kernel, dim3(sb), dim3(256), 0, stream, xbf,
                       (const unsigned short*)nullptr, T[1], rp, csr, N, 1.0f);
  for (int k = 2; k < K; ++k) {
    const unsigned short* prev = T[k - 2];
    hipLaunchKernelGGL(spmm_kernel, dim3(sb), dim3(256), 0, stream, T[k - 1], prev, T[k],
                       rp, csr, N, 2.0f);
  }

  // ---- W -> fragment-major bf16 ----
  int total = K * F * F;
  hipLaunchKernelGGL(convw_kernel, dim3((total + 255) / 256), dim3(256), 0, stream, W, Wt,
                     total);

  // ---- GEMM v7 ----
  GemmArgs ga;
  for (int k = 0; k < 8; ++k) ga.A[k] = (k < K) ? T[k] : xbf;
  ga.fc = fc; ga.Wt = Wt; ga.bias = bias;
  ga.out = (float*)d_out;
  ga.n = N; ga.kslices = K;
  hipLaunchKernelGGL(gemm_kernel, dim3((N + 127) / 128), dim3(512), 0, stream, ga);
}

// Round 11
// 319.133 us; speedup vs baseline: 1.1581x; 1.1581x over previous
//
#include <hip/hip_runtime.h>
#include <hip/hip_bf16.h>
#include <cstdio>

#define F 128
#define BSHIFT 9
#define BROWS 512   // rows per bucket (N must be <= 131072 for the 17-bit src pack)
#define C2 4096     // edges per bucket_scatter block

typedef __attribute__((ext_vector_type(4))) float f32x4;
typedef __attribute__((ext_vector_type(4))) unsigned short u16x4;
typedef __attribute__((ext_vector_type(8))) short s16x8;

__device__ inline unsigned short f2bf(float x) {
  unsigned int u = __float_as_uint(x);
  u += 0x7fffu + ((u >> 16) & 1u);   // RNE
  return (unsigned short)(u >> 16);
}
__device__ inline float bf2f(unsigned int h) {
  return __uint_as_float(h << 16);
}

__device__ inline void async_load16(const void* g, void* l) {
  __builtin_amdgcn_global_load_lds(
      (const __attribute__((address_space(1))) void*)g,
      (__attribute__((address_space(3))) void*)l, 16, 0, 0);
}

// ---------------- bucket histogram (LDS-aggregated) ----------------
__global__ void bucket_hist_kernel(const int* __restrict__ dst, int* __restrict__ bhist,
                                   int E, int B) {
  __shared__ int h[256];
  int t = threadIdx.x;
  h[t] = 0;
  __syncthreads();
  for (int e = blockIdx.x * blockDim.x + t; e < E; e += gridDim.x * blockDim.x)
    atomicAdd(&h[dst[e] >> BSHIFT], 1);
  __syncthreads();
  if (t < B && h[t]) atomicAdd(&bhist[t], h[t]);
}

// ---------------- bucket scan: bases (== rp at bucket boundaries) ----------------
__global__ void bucket_scan_kernel(const int* __restrict__ bhist, int* __restrict__ bbase,
                                   int* __restrict__ bcursor, int* __restrict__ rp,
                                   int E, int B, int N) {
  __shared__ int sm[256];
  int t = threadIdx.x;
  int v = (t < B) ? bhist[t] : 0;
  sm[t] = v;
  __syncthreads();
  int x = v;
  for (int off = 1; off < 256; off <<= 1) {
    int add = (t >= off) ? sm[t - off] : 0;
    __syncthreads();
    x += add;
    sm[t] = x;
    __syncthreads();
  }
  int excl = x - v;
  if (t < B) { bbase[t] = excl; bcursor[t] = excl; }
  if (t == 0) { bbase[B] = E; rp[N] = E; }
}

// ---------------- grouped bucket scatter: edges -> bucket-major staging ----------------
__global__ __launch_bounds__(256) void bucket_scatter_kernel(
    const int* __restrict__ src, const int* __restrict__ dst, const float* __restrict__ ew,
    int* __restrict__ bcursor, unsigned int* __restrict__ stg_p, float* __restrict__ stg_w,
    int E, int B) {
  __shared__ int hist[256], gbase[256], cur[256], sm[256], scn[256];
  __shared__ unsigned int sp[C2];
  __shared__ float swt[C2];
  __shared__ int sdest[C2];
  int t = threadIdx.x;
  int e0 = blockIdx.x * C2;
  int cnt = min(C2, E - e0);
  hist[t] = 0;
  __syncthreads();
#pragma unroll
  for (int i = 0; i < C2 / 256; ++i) {
    int e = e0 + t + i * 256;
    if (e < E) atomicAdd(&hist[dst[e] >> BSHIFT], 1);
  }
  __syncthreads();
  int v = hist[t];
  gbase[t] = (t < B && v) ? atomicAdd(&bcursor[t], v) : 0;
  sm[t] = v;
  __syncthreads();
  int x = v;
  for (int off = 1; off < 256; off <<= 1) {
    int add = (t >= off) ? sm[t - off] : 0;
    __syncthreads();
    x += add;
    sm[t] = x;
    __syncthreads();
  }
  scn[t] = x - v;
  cur[t] = 0;
  __syncthreads();
#pragma unroll
  for (int i = 0; i < C2 / 256; ++i) {
    int e = e0 + t + i * 256;
    if (e < E) {
      int d = dst[e];
      int b = d >> BSHIFT;
      int r = atomicAdd(&cur[b], 1);
      int slot = scn[b] + r;
      sp[slot] = (unsigned int)src[e] | ((unsigned int)(d & (BROWS - 1)) << 17);
      swt[slot] = ew[e];
      sdest[slot] = gbase[b] + r;
    }
  }
  __syncthreads();
#pragma unroll
  for (int i = 0; i < C2 / 256; ++i) {
    int s = t + i * 256;
    if (s < cnt) {
      int dpos = sdest[s];
      stg_p[dpos] = sp[s];
      stg_w[dpos] = swt[s];
    }
  }
}

// ---------------- per-bucket CSR finalize (also produces rp) ----------------
__global__ __launch_bounds__(256) void csr_build_kernel(
    const unsigned int* __restrict__ stg_p, const float* __restrict__ stg_w,
    const int* __restrict__ bbase, int* __restrict__ rp, int2* __restrict__ csr,
    int N, int B) {
  __shared__ int rhist[BROWS], rloc[BROWS], curp[BROWS];
  __shared__ int sm[256];
  int b = blockIdx.x, t = threadIdx.x;
  int row0 = b << BSHIFT;
  int base = bbase[b];
  int cnt = bbase[b + 1] - base;
  rhist[t] = 0;
  rhist[t + 256] = 0;
  __syncthreads();
  for (int s = base + t; s < base + cnt; s += 256)
    atomicAdd(&rhist[stg_p[s] >> 17], 1);
  __syncthreads();
  int a0 = rhist[2 * t], a1 = rhist[2 * t + 1];
  int pv = a0 + a1;
  sm[t] = pv;
  __syncthreads();
  int x = pv;
  for (int off = 1; off < 256; off <<= 1) {
    int add = (t >= off) ? sm[t - off] : 0;
    __syncthreads();
    x += add;
    sm[t] = x;
    __syncthreads();
  }
  int pexcl = x - pv;
  int r0 = 2 * t, r1 = 2 * t + 1;
  rloc[r0] = pexcl;
  rloc[r1] = pexcl + a0;
  if (row0 + r0 < N) rp[row0 + r0] = base + rloc[r0];
  if (row0 + r1 < N) rp[row0 + r1] = base + rloc[r1];
  curp[r0] = base + rloc[r0];
  curp[r1] = base + rloc[r1];
  __syncthreads();
  for (int s = base + t; s < base + cnt; s += 256) {
    unsigned int p = stg_p[s];
    int dl = p >> 17;
    int pos = atomicAdd(&curp[dl], 1);
    int2 entry;
    entry.x = (int)(p & 0x1ffffu);
    entry.y = __float_as_int(stg_w[s]);
    csr[pos] = entry;   // random 8B but confined to this bucket's ~64KB window
  }
}

// ---------------- x fp32 -> bf16 ----------------
__global__ void convx_kernel(const float* __restrict__ x, unsigned short* __restrict__ xbf,
                             int total4) {
  int i = blockIdx.x * 256 + threadIdx.x;
  if (i >= total4) return;
  f32x4 v = ((const f32x4*)x)[i];
  u16x4 o;
  o.x = f2bf(v.x); o.y = f2bf(v.y); o.z = f2bf(v.z); o.w = f2bf(v.w);
  ((u16x4*)xbf)[i] = o;
}

// ---------------- SPMM v4: 16-lane group per row, 8-deep gather pipeline ----------------
// Tout[r] = bf16( scale * sum_j w_j * Tin[src_j] - Tsub[r] )
__global__ __launch_bounds__(256) void spmm_kernel(
    const unsigned short* __restrict__ Tin, const unsigned short* __restrict__ Tsub,
    unsigned short* __restrict__ Tout, const int* __restrict__ rp,
    const int2* __restrict__ csr, int n, float scale) {
  int row = blockIdx.x * 16 + (threadIdx.x >> 4);
  if (row >= n) return;
  int sl = threadIdx.x & 15;   // 16B column slice within the row
  int j0 = rp[row], end = rp[row + 1];
  const uint4* Tin4 = (const uint4*)Tin;
  float acc[8];
#pragma unroll
  for (int c = 0; c < 8; ++c) acc[c] = 0.f;

  for (int j = j0; j < end; j += 8) {
    int2 e[8];
#pragma unroll
    for (int u = 0; u < 8; ++u)
      if (j + u < end) e[u] = csr[j + u];
    uint4 v[8];
#pragma unroll
    for (int u = 0; u < 8; ++u)
      if (j + u < end) v[u] = Tin4[(size_t)e[u].x * 16 + sl];
#pragma unroll
    for (int u = 0; u < 8; ++u) {
      if (j + u < end) {
        float w = __int_as_float(e[u].y);
        acc[0] = fmaf(w, bf2f(v[u].x & 0xffffu), acc[0]);
        acc[1] = fmaf(w, bf2f(v[u].x >> 16), acc[1]);
        acc[2] = fmaf(w, bf2f(v[u].y & 0xffffu), acc[2]);
        acc[3] = fmaf(w, bf2f(v[u].y >> 16), acc[3]);
        acc[4] = fmaf(w, bf2f(v[u].z & 0xffffu), acc[4]);
        acc[5] = fmaf(w, bf2f(v[u].z >> 16), acc[5]);
        acc[6] = fmaf(w, bf2f(v[u].w & 0xffffu), acc[6]);
        acc[7] = fmaf(w, bf2f(v[u].w >> 16), acc[7]);
      }
    }
  }

  float r[8];
#pragma unroll
  for (int c = 0; c < 8; ++c) r[c] = scale * acc[c];
  if (Tsub) {
    uint4 p = ((const uint4*)Tsub)[(size_t)row * 16 + sl];
    r[0] -= bf2f(p.x & 0xffffu); r[1] -= bf2f(p.x >> 16);
    r[2] -= bf2f(p.y & 0xffffu); r[3] -= bf2f(p.y >> 16);
    r[4] -= bf2f(p.z & 0xffffu); r[5] -= bf2f(p.z >> 16);
    r[6] -= bf2f(p.w & 0xffffu); r[7] -= bf2f(p.w >> 16);
  }
  uint4 o;
  o.x = (unsigned)f2bf(r[0]) | ((unsigned)f2bf(r[1]) << 16);
  o.y = (unsigned)f2bf(r[2]) | ((unsigned)f2bf(r[3]) << 16);
  o.z = (unsigned)f2bf(r[4]) | ((unsigned)f2bf(r[5]) << 16);
  o.w = (unsigned)f2bf(r[6]) | ((unsigned)f2bf(r[7]) << 16);
  ((uint4*)Tout)[(size_t)row * 16 + sl] = o;
}

// ---------------- W -> MFMA-fragment-major bf16 pack ----------------
// Wf[((ks*4+kk)*8+nt)*512 + lane*8 + j] = bf16(W[ks][kk*32+(lane>>4)*8+j][nt*16+(lane&15)])
__global__ void convw_kernel(const float* __restrict__ W, unsigned short* __restrict__ Wf,
                             int total) {
  int idx = blockIdx.x * 256 + threadIdx.x;
  if (idx >= total) return;
  int j = idx & 7;
  int lane = (idx >> 3) & 63;
  int nt = (idx >> 9) & 7;
  int kk = (idx >> 12) & 3;
  int ks = idx >> 14;
  int kl = kk * 32 + (lane >> 4) * 8 + j;
  int col = nt * 16 + (lane & 15);
  Wf[idx] = f2bf(W[(size_t)ks * F * F + (size_t)kl * F + col]);
}

// ---------------- GEMM v8: all-DMA double-buffered, counted vmcnt, swapped MFMA ------
// out[i,:] = sum_ks fc[ks,i] * (T_ks[i,:] @ W[ks]) + bias
// v7 skeleton (DMA staging, 0-conflict frag ds_reads) + T3/T4: stage(ks+1) before
// compute, s_waitcnt vmcnt(8) (never 0 mid-loop) + raw s_barrier -> loads in
// flight across barriers. MFMA operands swapped (a:=Wf frag, b:=T frag):
// D[m][n] = C[rowbase+n][colbase+m] -> lane holds 4 consecutive C-cols ->
// f32x4 epilogue stores; fc merge is a per-lane scalar.
struct GemmArgs {
  const unsigned short* A[8];
  const float* fc;
  const unsigned short* Wt;
  const float* bias;
  float* out;
  int n;
  int kslices;
};

__global__ __launch_bounds__(512) void gemm_kernel(GemmArgs args) {
  __shared__ __align__(16) unsigned short SA[2][16384];   // 2 x 32KB A frags
  __shared__ __align__(16) unsigned short SB[2][16384];   // 2 x 32KB B frags
  const int t = threadIdx.x;
  const int lane = t & 63;
  const int wid = t >> 6;          // 0..7
  const int wrow = wid >> 1;       // 0..3 (32-row slice)
  const int wcol = wid & 1;        // 0..1 (64-col slice)
  const int n = args.n;
  const int KS = args.kslices;
  const int bm = blockIdx.x * 128;
  const int arow = lane & 15;
  const int kg = lane >> 4;

  // per-wave staging: frags fi = wid + i*8 (4 A frags + 4 B frags = 8 loads/wave)
  auto stage = [&](int ks, int b) {
    const unsigned short* As = args.A[ks];
#pragma unroll
    for (int i = 0; i < 4; ++i) {
      int fi = wid + i * 8;
      int rg = fi >> 2, kk = fi & 3;
      int r = bm + rg * 16 + arow;
      if (r >= n) r = n - 1;
      async_load16((const void*)(As + (size_t)r * F + kk * 32 + kg * 8),
                   (void*)(SA[b] + fi * 512));
    }
#pragma unroll
    for (int i = 0; i < 4; ++i) {
      int fi = wid + i * 8;
      async_load16((const void*)(args.Wt + (size_t)ks * 16384 + fi * 512 + lane * 8),
                   (void*)(SB[b] + fi * 512));
    }
  };

  f32x4 Cf[2][4];
#pragma unroll
  for (int mt = 0; mt < 2; ++mt)
#pragma unroll
    for (int nt = 0; nt < 4; ++nt) Cf[mt][nt] = (f32x4){0.f, 0.f, 0.f, 0.f};

  // fc rows this lane owns (C-row = bm + wrow*32 + mt*16 + arow)
  int row_c[2];
#pragma unroll
  for (int mt = 0; mt < 2; ++mt) {
    int r = bm + wrow * 32 + mt * 16 + arow;
    row_c[mt] = r < n ? r : n - 1;
  }

  stage(0, 0);

  for (int ks = 0; ks < KS; ++ks) {
    const int b = ks & 1;
    if (ks + 1 < KS) {
      stage(ks + 1, b ^ 1);
      asm volatile("s_waitcnt vmcnt(8)" ::: "memory");  // ks's 8 loads done; ks+1 in flight
    } else {
      asm volatile("s_waitcnt vmcnt(0)" ::: "memory");
    }
    __builtin_amdgcn_sched_barrier(0);
    __builtin_amdgcn_s_barrier();
    __builtin_amdgcn_sched_barrier(0);

    // fc scalars for merge (independent of MFMA chain; overlaps)
    float fv[2];
#pragma unroll
    for (int mt = 0; mt < 2; ++mt) fv[mt] = args.fc[(size_t)ks * n + row_c[mt]];

    f32x4 acc[2][4];
#pragma unroll
    for (int mt = 0; mt < 2; ++mt)
#pragma unroll
      for (int nt = 0; nt < 4; ++nt) acc[mt][nt] = (f32x4){0.f, 0.f, 0.f, 0.f};

#pragma unroll
    for (int kk = 0; kk < 4; ++kk) {
      s16x8 af[2], bfr[4];
#pragma unroll
      for (int mt = 0; mt < 2; ++mt) {
        int rg = wrow * 2 + mt;
        af[mt] = *(const s16x8*)&SA[b][(rg * 4 + kk) * 512 + lane * 8];
      }
#pragma unroll
      for (int nt = 0; nt < 4; ++nt)
        bfr[nt] = *(const s16x8*)&SB[b][(kk * 8 + wcol * 4 + nt) * 512 + lane * 8];
      // swapped operands: D[m][n] = C^T tile -> lane holds 4 consecutive C-cols
#pragma unroll
      for (int mt = 0; mt < 2; ++mt)
#pragma unroll
        for (int nt = 0; nt < 4; ++nt)
          acc[mt][nt] = __builtin_amdgcn_mfma_f32_16x16x32_bf16(bfr[nt], af[mt],
                                                                acc[mt][nt], 0, 0, 0);
    }

#pragma unroll
    for (int mt = 0; mt < 2; ++mt)
#pragma unroll
      for (int nt = 0; nt < 4; ++nt) Cf[mt][nt] += fv[mt] * acc[mt][nt];

    __builtin_amdgcn_sched_barrier(0);
    __builtin_amdgcn_s_barrier();   // frag reads done before this buffer is restaged
    __builtin_amdgcn_sched_barrier(0);
  }

  // epilogue: lane holds C[row = bm+wrow*32+mt*16+arow][col = (wcol*4+nt)*16+kg*4 ..+4]
#pragma unroll
  for (int mt = 0; mt < 2; ++mt) {
    int row = bm + wrow * 32 + mt * 16 + arow;
    if (row >= n) continue;
#pragma unroll
    for (int nt = 0; nt < 4; ++nt) {
      int col = (wcol * 4 + nt) * 16 + kg * 4;
      f32x4 bv = *(const f32x4*)(args.bias + col);
      *(f32x4*)(args.out + (size_t)row * F + col) = Cf[mt][nt] + bv;
    }
  }
}

extern "C" void kernel_launch(void* const* d_in, const int* in_sizes, int n_in,
                              void* d_out, int out_size, void* d_ws, size_t ws_size,
                              hipStream_t stream) {
  const float* x    = (const float*)d_in[0];
  const float* fc   = (const float*)d_in[1];
  const float* W    = (const float*)d_in[2];
  const float* bias = (const float*)d_in[3];
  const float* ew   = (const float*)d_in[4];
  const int*   src  = (const int*)d_in[5];
  const int*   dst  = (const int*)d_in[6];

  const int N = in_sizes[0] / F;
  const int K = in_sizes[2] / (F * F);
  const int E = in_sizes[4];
  const int B = (N + BROWS - 1) >> BSHIFT;   // buckets; requires N <= 131072

  size_t off = 0;
  char* base = (char*)d_ws;
  auto alloc = [&](size_t bytes) -> void* {
    void* p = base + off;
    off += (bytes + 511) & ~(size_t)511;
    return p;
  };
  int* rp              = (int*)alloc(((size_t)N + 1) * 4);
  int* bhist           = (int*)alloc(1024);
  int* bbase           = (int*)alloc(1040);
  int* bcursor         = (int*)alloc(1024);
  int2* csr            = (int2*)alloc((size_t)E * 8);
  unsigned short* Wt   = (unsigned short*)alloc((size_t)K * F * F * 2);
  unsigned short* xbf  = (unsigned short*)alloc((size_t)N * F * 2);
  unsigned short* T[8];
  T[0] = xbf;
  for (int k = 1; k < K && k < 8; ++k) T[k] = (unsigned short*)alloc((size_t)N * F * 2);
  // staging aliased onto T[2] (written only after CSR build); fallback alloc if K<3
  unsigned int* stg_p;
  float* stg_w;
  if (K >= 3 && (size_t)N * F * 2 >= (size_t)E * 8) {
    stg_p = (unsigned int*)T[2];
    stg_w = (float*)(T[2] + (size_t)E * 2);  // E*2 ushorts == E*4 bytes
  } else {
    stg_p = (unsigned int*)alloc((size_t)E * 4);
    stg_w = (float*)alloc((size_t)E * 4);
  }
  if (off > ws_size) {
    fprintf(stderr, "kernel_launch: ws too small: need %zu have %zu\n", off, ws_size);
    return;
  }

  // ---- CSR build (bucketed) ----
  hipMemsetAsync(bhist, 0, 1024, stream);
  hipLaunchKernelGGL(bucket_hist_kernel, dim3(208), dim3(256), 0, stream, dst, bhist, E, B);
  hipLaunchKernelGGL(bucket_scan_kernel, dim3(1), dim3(256), 0, stream, bhist, bbase, bcursor,
                     rp, E, B, N);
  int sblocks = (E + C2 - 1) / C2;
  hipLaunchKernelGGL(bucket_scatter_kernel, dim3(sblocks), dim3(256), 0, stream, src, dst, ew,
                     bcursor, stg_p, stg_w, E, B);
  hipLaunchKernelGGL(csr_build_kernel, dim3(B), dim3(256), 0, stream, stg_p, stg_w, bbase,
                     rp, csr, N, B);

  // ---- x -> bf16 ----
  int total4 = N * F / 4;
  hipLaunchKernelGGL(convx_kernel, dim3((total4 + 255) / 256), dim3(256), 0, stream,
                     x, xbf, total4);

  // ---- Chebyshev recurrence (bf16 state, fp32 accum) ----
  int sb = (N + 15) / 16;  // 16 rows (16-lane groups) per 256-thread block
  if (K > 1)
    hipLaunchKernelGGL(spmm_kernel, dim3(sb), dim3(256), 0, stream, xbf,
                       (const unsigned short*)nullptr, T[1], rp, csr, N, 1.0f);
  for (int k = 2; k < K; ++k) {
    const unsigned short* prev = T[k - 2];
    hipLaunchKernelGGL(spmm_kernel, dim3(sb), dim3(256), 0, stream, T[k - 1], prev, T[k],
                       rp, csr, N, 2.0f);
  }

  // ---- W -> fragment-major bf16 ----
  int total = K * F * F;
  hipLaunchKernelGGL(convw_kernel, dim3((total + 255) / 256), dim3(256), 0, stream, W, Wt,
                     total);

  // ---- GEMM v8 ----
  GemmArgs ga;
  for (int k = 0; k < 8; ++k) ga.A[k] = (k < K) ? T[k] : xbf;
  ga.fc = fc; ga.Wt = Wt; ga.bias = bias;
  ga.out = (float*)d_out;
  ga.n = N; ga.kslices = K;
  hipLaunchKernelGGL(gemm_kernel, dim3((N + 127) / 128), dim3(512), 0, stream, ga);
}